// Round 16
// baseline (359.702 us; speedup 1.0000x reference)
//
#include <hip/hip_runtime.h>

#define N_NODES 50000
#define N_HEDGES 5000
#define NNZ 800000
#define IN_C 128
#define D1 256
#define D2 64
#define SN 64    // fixed stride: hedges per node row (deg mean 16, 12 sigma safe)
#define SH 256   // fixed stride: nodes per hedge row (deg mean 160, 7.6 sigma safe)

// dummy indices for adjacency padding (point at zeroed feature rows)
#define DUMN 50000   // dummy node index (row 50000 of xb/hwb zeroed)
#define DUMH 5000    // dummy hedge index (row 5000 of aggxb/e2b zeroed)

// bucketed adjacency build
#define HBK 20     // hedges per bucket
#define NHB 250    // hedge buckets
#define HCAP 4096  // pair capacity per hedge bucket (mean 3200, 16 sigma)
#define NBK 100    // nodes per bucket
#define NNB 500    // node buckets
#define NCAP 2048  // pair capacity per node bucket (mean 1600, 11 sigma)
#define BKT_BLOCKS ((NNZ + 2047) / 2048)   // 391

typedef unsigned int u32;
typedef unsigned short u16;
typedef __attribute__((ext_vector_type(8))) short short8;
typedef __attribute__((ext_vector_type(4))) float f32x4;

// ---- bf16 helpers: storage bf16, math f32 ----
__device__ __forceinline__ float bf_lo(u32 u) { return __uint_as_float(u << 16); }
__device__ __forceinline__ float bf_hi(u32 u) { return __uint_as_float(u & 0xffff0000u); }
__device__ __forceinline__ u32 rne16(float f) {
    u32 u = __float_as_uint(f);
    return (u + 0x7fffu + ((u >> 16) & 1u)) >> 16;
}
__device__ __forceinline__ u32 pack2(float a, float b) {
    return rne16(a) | (rne16(b) << 16);
}
__device__ __forceinline__ void acc8(float* a, uint4 v) {
    a[0] += bf_lo(v.x); a[1] += bf_hi(v.x);
    a[2] += bf_lo(v.y); a[3] += bf_hi(v.y);
    a[4] += bf_lo(v.z); a[5] += bf_hi(v.z);
    a[6] += bf_lo(v.w); a[7] += bf_hi(v.w);
}

// ---------------- fused: cast x->bf16 + pack W1/W2 + bucket edges + zero dummy rows ----------------
__global__ void cast_bucket(const float4* __restrict__ x, uint2* __restrict__ xb,
                            const float* __restrict__ W1, u16* __restrict__ w1hi,
                            u16* __restrict__ w1lo,
                            const float* __restrict__ W2, u16* __restrict__ w2hi,
                            u16* __restrict__ w2lo,
                            const int* __restrict__ nidx, const int* __restrict__ hidx,
                            int* __restrict__ gcur_h, int* __restrict__ gcur_n,
                            u32* __restrict__ pairs_h, u32* __restrict__ pairs_n,
                            uint4* __restrict__ xbz, uint4* __restrict__ aggz,
                            uint4* __restrict__ hwz, uint4* __restrict__ e2z) {
    __shared__ int hist_h[NHB], hist_n[NNB];
    __shared__ int base_h[NHB], base_n[NNB];
    int tid = threadIdx.x;
    int i = blockIdx.x * 256 + tid;
    float4 v = x[i];
    uint2 o;
    o.x = pack2(v.x, v.y);
    o.y = pack2(v.z, v.w);
    xb[i] = o;
    if (i < 32768) {  // W1: kc=0..3 (K=128), ct=0..15 (N=256)
        int j = i & 7;
        int l = (i >> 3) & 63;
        int ct = (i >> 9) & 15;
        int kc = i >> 13;
        int k = kc * 32 + (l >> 4) * 8 + j;
        int n = ct * 16 + (l & 15);
        float w = W1[k * D1 + n];
        u32 h = rne16(w);
        w1hi[i] = (u16)h;
        w1lo[i] = (u16)rne16(w - bf_lo(h));
    } else if (i < 32768 + 16384) {  // W2: kc=0..7 (K=256), nt=0..3 (N=64)
        int t = i - 32768;
        int j = t & 7;
        int l = (t >> 3) & 63;
        int nt = (t >> 9) & 3;
        int kc = t >> 11;
        int k = kc * 32 + (l >> 4) * 8 + j;
        int n = nt * 16 + (l & 15);
        float w = W2[k * D2 + n];
        u32 h = rne16(w);
        w2hi[t] = (u16)h;
        w2lo[t] = (u16)rne16(w - bf_lo(h));
    }
    // zero the dummy feature rows (gather targets for padded adjacency slots)
    if (blockIdx.x == gridDim.x - 1) {
        uint4 z = make_uint4(0u, 0u, 0u, 0u);
        if (tid < 16) xbz[tid] = z;            // xb row DUMN: 256 B
        else if (tid < 32) aggz[tid - 16] = z; // aggxb row DUMH: 256 B
        else if (tid < 40) hwz[tid - 32] = z;  // hwb row DUMN: 128 B
        else if (tid < 48) e2z[tid - 40] = z;  // e2b row DUMH: 128 B
    }
    if (blockIdx.x >= BKT_BLOCKS) return;
    for (int t = tid; t < NHB; t += 256) hist_h[t] = 0;
    for (int t = tid; t < NNB; t += 256) hist_n[t] = 0;
    __syncthreads();
    int e0 = blockIdx.x * 2048 + tid * 8;
    int ns[8], hs_[8];
#pragma unroll
    for (int k = 0; k < 8; k++) {
        int e = e0 + k;
        if (e < NNZ) {
            ns[k] = nidx[e];
            hs_[k] = hidx[e];
            atomicAdd(&hist_h[hs_[k] / HBK], 1);
            atomicAdd(&hist_n[ns[k] / NBK], 1);
        } else {
            ns[k] = -1;
        }
    }
    __syncthreads();
    if (tid < NHB) base_h[tid] = atomicAdd(&gcur_h[tid], hist_h[tid]);
    for (int t = tid; t < NNB; t += 256) base_n[t] = atomicAdd(&gcur_n[t], hist_n[t]);
    __syncthreads();
    for (int t = tid; t < NHB; t += 256) hist_h[t] = 0;
    for (int t = tid; t < NNB; t += 256) hist_n[t] = 0;
    __syncthreads();
#pragma unroll
    for (int k = 0; k < 8; k++) {
        if (ns[k] >= 0) {
            int n = ns[k], h = hs_[k];
            int bh = h / HBK, bn = n / NBK;
            int s1 = base_h[bh] + atomicAdd(&hist_h[bh], 1);
            if (s1 < HCAP) pairs_h[bh * HCAP + s1] = ((u32)h << 16) | (u32)n;
            int s2 = base_n[bn] + atomicAdd(&hist_n[bn], 1);
            if (s2 < NCAP) pairs_n[bn * NCAP + s2] = ((u32)n << 16) | (u32)h;
        }
    }
}

// ---------------- build adjacency rows in LDS, write coalesced (both sides) ----------------
__global__ void build_adj(const u32* __restrict__ pairs_h, const int* __restrict__ gcur_h,
                          u16* __restrict__ adj_h, int* __restrict__ cur_h,
                          const u32* __restrict__ pairs_n, const int* __restrict__ gcur_n,
                          u16* __restrict__ adj_n, int* __restrict__ cur_n) {
    __shared__ u16 rows[NBK * SN];  // 12.8 KB (>= HBK*SH = 10.24 KB)
    __shared__ int cnt[NBK];        // >= HBK
    int tid = threadIdx.x;
    if (blockIdx.x < NHB) {
        int b = blockIdx.x;
        if (tid < HBK) cnt[tid] = 0;
        {
            u32* rw = (u32*)rows;
            for (int t = tid; t < HBK * SH / 2; t += 256) rw[t] = (DUMN << 16) | DUMN;
        }
        __syncthreads();
        int np = gcur_h[b];
        if (np > HCAP) np = HCAP;
        for (int t = tid; t < np; t += 256) {
            u32 p = pairs_h[b * HCAP + t];
            int hl = (int)(p >> 16) - b * HBK;
            int s = atomicAdd(&cnt[hl], 1);
            if (s < SH) rows[hl * SH + s] = (u16)(p & 0xffff);
        }
        __syncthreads();
        u32* dst = (u32*)(adj_h + b * HBK * SH);
        const u32* srcl = (const u32*)rows;
        for (int t = tid; t < HBK * SH / 2; t += 256) dst[t] = srcl[t];
        if (tid < HBK) cur_h[b * HBK + tid] = cnt[tid];
    } else {
        int b = blockIdx.x - NHB;
        if (tid < NBK) cnt[tid] = 0;
        {
            u32* rw = (u32*)rows;
            for (int t = tid; t < NBK * SN / 2; t += 256) rw[t] = (DUMH << 16) | DUMH;
        }
        __syncthreads();
        int np = gcur_n[b];
        if (np > NCAP) np = NCAP;
        for (int t = tid; t < np; t += 256) {
            u32 p = pairs_n[b * NCAP + t];
            int nl = (int)(p >> 16) - b * NBK;
            int s = atomicAdd(&cnt[nl], 1);
            if (s < SN) rows[nl * SN + s] = (u16)(p & 0xffff);
        }
        __syncthreads();
        u32* dst = (u32*)(adj_n + b * NBK * SN);
        const u32* srcl = (const u32*)rows;
        for (int t = tid; t < NBK * SN / 2; t += 256) dst[t] = srcl[t];
        if (tid < NBK) cur_n[b * NBK + tid] = cnt[tid];
    }
}

// ---- shared gather core: remainder-free (dummy-padded adj), adj one group ahead ----
template <int L>
__device__ __forceinline__ void gcore(const uint4* __restrict__ src,
                                      const u16* __restrict__ arow,
                                      int js, int je, int c,
                                      float* a0, float* a1, float* a2, float* a3) {
    if (js >= je) return;
    uint4 aa = *(const uint4*)(arow + js);
    for (int j = js; j < je; j += 8) {
        uint4 nx = aa;
        if (j + 8 < je) nx = *(const uint4*)(arow + j + 8);
        int i0 = aa.x & 0xffff, i1 = aa.x >> 16;
        int i2 = aa.y & 0xffff, i3 = aa.y >> 16;
        int i4 = aa.z & 0xffff, i5 = aa.z >> 16;
        int i6 = aa.w & 0xffff, i7 = aa.w >> 16;
        uint4 v0 = src[i0 * L + c];
        uint4 v1 = src[i1 * L + c];
        uint4 v2 = src[i2 * L + c];
        uint4 v3 = src[i3 * L + c];
        uint4 v4 = src[i4 * L + c];
        uint4 v5 = src[i5 * L + c];
        uint4 v6 = src[i6 * L + c];
        uint4 v7 = src[i7 * L + c];
        acc8(a0, v0); acc8(a1, v1); acc8(a2, v2); acc8(a3, v3);
        acc8(a0, v4); acc8(a1, v5); acc8(a2, v6); acc8(a3, v7);
        aa = nx;
    }
}

// ---------------- split-K hedge gather: L*SPLIT threads/row, LDS combine ----------------
template <int F, int S, int SPLIT>
__global__ __launch_bounds__(256, 2)
void gather_split(const uint4* __restrict__ src, const int* __restrict__ cur,
                  const u16* __restrict__ adj, uint4* __restrict__ dst,
                  int nrows) {
    constexpr int L = F / 8;
    constexpr int TR = L * SPLIT;       // threads per row
    constexpr int RB = 256 / TR;        // rows per block
    constexpr int CHUNK = S / SPLIT;
    int tid = threadIdx.x;
    int rl = tid / TR;
    int seg = (tid % TR) / L;
    int c = tid % L;
    int row = blockIdx.x * RB + rl;
    bool valid = row < nrows;
    int len = valid ? cur[row] : 0;
    int lenc = (len < S) ? len : S;
    int lenp = (lenc + 7) & ~7;          // padded length (adj has dummies past cnt)
    int js = seg * CHUNK;
    int je = (lenp < js + CHUNK) ? lenp : (js + CHUNK);
    float a0[8] = {0,0,0,0,0,0,0,0}, a1[8] = {0,0,0,0,0,0,0,0};
    float a2[8] = {0,0,0,0,0,0,0,0}, a3[8] = {0,0,0,0,0,0,0,0};
    if (valid)
        gcore<L>(src, adj + row * S, js, je, c, a0, a1, a2, a3);
    // per-(rl,c,seg) partial -> LDS: RB*L*SPLIT*8 = 256*8 floats = 8KB
    __shared__ float partf[256][8];
#pragma unroll
    for (int t = 0; t < 8; t++) partf[tid][t] = ((a0[t] + a1[t]) + (a2[t] + a3[t]));
    __syncthreads();
    if (seg == 0 && valid) {
        float r[8];
#pragma unroll
        for (int t = 0; t < 8; t++) r[t] = partf[tid][t];
#pragma unroll
        for (int s2 = 1; s2 < SPLIT; s2++) {
#pragma unroll
            for (int t = 0; t < 8; t++) r[t] += partf[tid + s2 * L][t];
        }
        float inv = (len > 0) ? 1.f / (float)len : 0.f;
        uint4 o;
        o.x = pack2(r[0] * inv, r[1] * inv);
        o.y = pack2(r[2] * inv, r[3] * inv);
        o.z = pack2(r[4] * inv, r[5] * inv);
        o.w = pack2(r[6] * inv, r[7] * inv);
        dst[row * L + c] = o;
    }
}

// ---------------- bf16-source pull-gather (node side), vec-adj, remainder-free ----------------
template <int F, int S, bool BIAS_RELU, bool DST_BF16>
__global__ __launch_bounds__(256, 2)
void gatherb(const uint4* __restrict__ src, const int* __restrict__ cur,
             const u16* __restrict__ adj, const float4* __restrict__ bias,
             void* __restrict__ dst, int nrows) {
    constexpr int L = F / 8;
    int gid = blockIdx.x * 256 + threadIdx.x;
    int row = gid / L;
    if (row >= nrows) return;
    int c = gid - row * L;
    int len = cur[row];
    int lenc = (len < S) ? len : S;
    int lenp = (lenc + 7) & ~7;          // padded length (adj has dummies past cnt)
    float a0[8] = {0,0,0,0,0,0,0,0}, a1[8] = {0,0,0,0,0,0,0,0};
    float a2[8] = {0,0,0,0,0,0,0,0}, a3[8] = {0,0,0,0,0,0,0,0};
    gcore<L>(src, adj + row * S, 0, lenp, c, a0, a1, a2, a3);
    float inv = (len > 0) ? 1.f / (float)len : 0.f;
    float r[8];
#pragma unroll
    for (int t = 0; t < 8; t++) r[t] = ((a0[t] + a1[t]) + (a2[t] + a3[t])) * inv;
    if (BIAS_RELU) {
        float4 b0 = bias[c * 2], b1v = bias[c * 2 + 1];
        r[0] = fmaxf(r[0] + b0.x, 0.f); r[1] = fmaxf(r[1] + b0.y, 0.f);
        r[2] = fmaxf(r[2] + b0.z, 0.f); r[3] = fmaxf(r[3] + b0.w, 0.f);
        r[4] = fmaxf(r[4] + b1v.x, 0.f); r[5] = fmaxf(r[5] + b1v.y, 0.f);
        r[6] = fmaxf(r[6] + b1v.z, 0.f); r[7] = fmaxf(r[7] + b1v.w, 0.f);
    }
    if (DST_BF16) {
        uint4 o;
        o.x = pack2(r[0], r[1]);
        o.y = pack2(r[2], r[3]);
        o.z = pack2(r[4], r[5]);
        o.w = pack2(r[6], r[7]);
        ((uint4*)dst)[row * L + c] = o;
    } else {
        float4* d = (float4*)dst;
        d[row * (F / 4) + c * 2]     = make_float4(r[0], r[1], r[2], r[3]);
        d[row * (F / 4) + c * 2 + 1] = make_float4(r[4], r[5], r[6], r[7]);
    }
}

// ---------------- MLP: hw = relu(sb@W1+b1)@W2 — staged-in / coalesced-out rev ----------------
// r15 best (197.9 total). IDEMPOTENT: reps>1 recomputes identical hw —
// INSTRUMENTATION this round: reps=6 surfaces this kernel in the rocprof
// top-5 with post-fix counters (FETCH/WRITE per rep, MfmaUtil, Occupancy).
#define SB_STRIDE 136
#define HSTRIDE 264
#define OSTR 72
__global__ __launch_bounds__(256, 3)
void mlp64(const uint4* __restrict__ sb4,
           const short8* __restrict__ w1hi, const short8* __restrict__ w1lo,
           const float* __restrict__ b1,
           const short8* __restrict__ w2hi, const short8* __restrict__ w2lo,
           u16* __restrict__ hw, int reps) {
    __shared__ u16 hs[64 * HSTRIDE];     // 33792 B
    __shared__ u16 sbs[64 * SB_STRIDE];  // 17408 B (reused as output stage; >= 64*OSTR*2)
    int tid = threadIdx.x;
    int node0 = blockIdx.x * 64;
    int wave = tid >> 6;
    int lane = tid & 63;
    int m = lane & 15;
    int q = lane >> 4;
    for (int rep = 0; rep < reps; rep++) {
        asm volatile("" ::: "memory");
        // ---- stage sb tile: 64 nodes x 256 B = 16 KB, coalesced ----
        {
            int nl = tid >> 4;   // 0..15
            int c = tid & 15;    // uint4 col 0..15
#pragma unroll
            for (int p = 0; p < 4; p++) {
                uint4 v = sb4[(node0 + p * 16 + nl) * 16 + c];
                *(uint4*)&sbs[(p * 16 + nl) * SB_STRIDE + c * 8] = v;
            }
        }
        __syncthreads();
        // ---- W1 phase: wave handles ct = wave*4+i (i=0..3), all 4 m-tiles ----
        f32x4 acc[4][4];  // [i][mt], bias folded into init
#pragma unroll
        for (int i = 0; i < 4; i++) {
            float bc = b1[(wave * 4 + i) * 16 + m];
#pragma unroll
            for (int mt = 0; mt < 4; mt++)
                acc[i][mt] = (f32x4){bc, bc, bc, bc};
        }
#pragma unroll
        for (int kc = 0; kc < 4; kc++) {
            short8 am[4];
#pragma unroll
            for (int mt = 0; mt < 4; mt++)
                am[mt] = *(const short8*)&sbs[(mt * 16 + m) * SB_STRIDE + kc * 32 + q * 8];
            short8 w[4];
#pragma unroll
            for (int i = 0; i < 4; i++)
                w[i] = w1hi[(kc * 16 + wave * 4 + i) * 64 + lane];
#pragma unroll
            for (int i = 0; i < 4; i++)
#pragma unroll
                for (int mt = 0; mt < 4; mt++)
                    acc[i][mt] = __builtin_amdgcn_mfma_f32_16x16x32_bf16(am[mt], w[i], acc[i][mt], 0, 0, 0);
#pragma unroll
            for (int i = 0; i < 4; i++)
                w[i] = w1lo[(kc * 16 + wave * 4 + i) * 64 + lane];
#pragma unroll
            for (int i = 0; i < 4; i++)
#pragma unroll
                for (int mt = 0; mt < 4; mt++)
                    acc[i][mt] = __builtin_amdgcn_mfma_f32_16x16x32_bf16(am[mt], w[i], acc[i][mt], 0, 0, 0);
        }
#pragma unroll
        for (int i = 0; i < 4; i++) {
            int col = (wave * 4 + i) * 16 + m;   // C layout: col = lane&15, row = q*4+r
#pragma unroll
            for (int mt = 0; mt < 4; mt++)
#pragma unroll
                for (int r = 0; r < 4; r++) {
                    float h = fmaxf(acc[i][mt][r], 0.f);
                    hs[(mt * 16 + q * 4 + r) * HSTRIDE + col] = (u16)rne16(h);
                }
        }
        __syncthreads();   // all sbs reads done; sbs reusable as output stage
        // ---- W2 phase: wave handles nt = wave, all 4 m-tiles ----
        f32x4 acc2[4];
#pragma unroll
        for (int mt = 0; mt < 4; mt++) acc2[mt] = (f32x4){0.f, 0.f, 0.f, 0.f};
#pragma unroll
        for (int kc = 0; kc < 8; kc++) {
            short8 ah[4];
#pragma unroll
            for (int mt = 0; mt < 4; mt++)
                ah[mt] = *(const short8*)&hs[(mt * 16 + m) * HSTRIDE + kc * 32 + q * 8];
            short8 whi = w2hi[(kc * 4 + wave) * 64 + lane];
#pragma unroll
            for (int mt = 0; mt < 4; mt++)
                acc2[mt] = __builtin_amdgcn_mfma_f32_16x16x32_bf16(ah[mt], whi, acc2[mt], 0, 0, 0);
            short8 wlo = w2lo[(kc * 4 + wave) * 64 + lane];
#pragma unroll
            for (int mt = 0; mt < 4; mt++)
                acc2[mt] = __builtin_amdgcn_mfma_f32_16x16x32_bf16(ah[mt], wlo, acc2[mt], 0, 0, 0);
        }
        // ---- gather output tile in LDS, then coalesced 128B-line stores ----
#pragma unroll
        for (int mt = 0; mt < 4; mt++)
#pragma unroll
            for (int r = 0; r < 4; r++)
                sbs[(mt * 16 + q * 4 + r) * OSTR + wave * 16 + m] = (u16)rne16(acc2[mt][r]);
        __syncthreads();
        {
            // 64 nodes x 8 uint4 (128 B) = 512 uint4; 256 threads x 2 passes
#pragma unroll
            for (int p = 0; p < 2; p++) {
                int idx = p * 256 + tid;
                int nl = idx >> 3;
                int c = idx & 7;
                int node = node0 + nl;
                if (node < N_NODES)
                    ((uint4*)hw)[node * 8 + c] = *(const uint4*)&sbs[nl * OSTR + c * 8];
            }
        }
        __syncthreads();   // protect sbs (out-stage) before next rep re-stages it
    }
}

extern "C" void kernel_launch(void* const* d_in, const int* in_sizes, int n_in,
                              void* d_out, int out_size, void* d_ws, size_t ws_size,
                              hipStream_t stream) {
    const float* x  = (const float*)d_in[0];
    const int* edge = (const int*)d_in[1];
    const int* nidx = edge;         // edge[0, :]
    const int* hidx = edge + NNZ;   // edge[1, :]
    const float* W1 = (const float*)d_in[2];
    const float* b1 = (const float*)d_in[3];
    const float* W2 = (const float*)d_in[4];
    const float* b2 = (const float*)d_in[5];
    float* out = (float*)d_out;

    // ---- workspace layout (all chunks 16B-aligned; +1 zeroed dummy row each) ----
    u16* xb     = (u16*)d_ws;                       // (50000+1)*128 u16
    u16* aggxb  = xb + (N_NODES + 1) * IN_C;        // (5000+1)*128  u16
    u16* hwb    = aggxb + (N_HEDGES + 1) * IN_C;    // (50000+1)*64  u16
    u16* e2b    = hwb + (N_NODES + 1) * D2;         // (5000+1)*64   u16
    u16* w1hi   = e2b + (N_HEDGES + 1) * D2;        // 32768 u16
    u16* w1lo   = w1hi + 32768;               // 32768 u16
    u16* w2hi   = w1lo + 32768;               // 16384 u16
    u16* w2lo   = w2hi + 16384;               // 16384 u16
    u16* adj_n  = w2lo + 16384;               // 50000*64 u16 = 3,200,000
    u16* adj_h  = adj_n + N_NODES * SN;       // 5000*256 u16 = 1,280,000
    u32* pairs_h = (u32*)(adj_h + N_HEDGES * SH); // 250*4096 u32 = 4 MB
    u32* pairs_n = pairs_h + NHB * HCAP;          // 500*2048 u32 = 4 MB
    int* cur_n  = (int*)(pairs_n + NNB * NCAP);   // 50000 (written by build)
    int* cur_h  = cur_n + N_NODES;                // 5000  (written by build)
    int* gcur_h = cur_h + N_HEDGES;               // 256 (zeroed)
    int* gcur_n = gcur_h + 256;                   // 512 (zeroed)
    u16* sb     = (u16*)(gcur_n + 512);           // 50048*128 u16 = 12.8 MB (padded tail)
    // total ≈ 52 MB

    hipMemsetAsync(gcur_h, 0, (256 + 512) * sizeof(int), stream);

    // fused: cast + W-pack + bucket + zero dummy rows
    cast_bucket<<<N_NODES * IN_C / 4 / 256, 256, 0, stream>>>(
        (const float4*)x, (uint2*)xb, W1, w1hi, w1lo, W2, w2hi, w2lo,
        nidx, hidx, gcur_h, gcur_n, pairs_h, pairs_n,
        (uint4*)(xb + DUMN * IN_C), (uint4*)(aggxb + DUMH * IN_C),
        (uint4*)(hwb + DUMN * D2), (uint4*)(e2b + DUMH * D2));

    build_adj<<<NHB + NNB, 256, 0, stream>>>(pairs_h, gcur_h, adj_h, cur_h,
                                             pairs_n, gcur_n, adj_n, cur_n);

    // aggxb = Binv * gather_h(xb)   [5000 x 128 bf16]  — split-K x4 (64 thr/row)
    gather_split<IN_C, SH, 4><<<(N_HEDGES + 3) / 4, 256, 0, stream>>>(
        (const uint4*)xb, cur_h, adj_h, (uint4*)aggxb, N_HEDGES);

    // sb = Dinv * gather_n(aggxb)   [50000 x 128 bf16] — no-LDS pull gather
    gatherb<IN_C, SN, false, true><<<(N_NODES * (IN_C / 8) + 255) / 256, 256, 0, stream>>>(
        (const uint4*)aggxb, cur_n, adj_n, (const float4*)b1, (void*)sb, N_NODES);

    // hw = relu(sb@W1+b1)@W2  — INSTRUMENTED x6 (idempotent; surfaces counters)
    mlp64<<<(N_NODES + 63) / 64, 256, 0, stream>>>(
        (const uint4*)sb, (const short8*)w1hi, (const short8*)w1lo, b1,
        (const short8*)w2hi, (const short8*)w2lo, hwb, 6);

    // layer 2: e2b = Binv * gather_h(hwb)  — split-K x8 (64 thr/row)
    gather_split<D2, SH, 8><<<(N_HEDGES + 3) / 4, 256, 0, stream>>>(
        (const uint4*)hwb, cur_h, adj_h, (uint4*)e2b, N_HEDGES);
    // out = relu(Dinv * gather_n(e2b) + b2)   [50000 x 64 f32]
    gatherb<D2, SN, true, false><<<(N_NODES * (D2 / 8) + 255) / 256, 256, 0, stream>>>(
        (const uint4*)e2b, cur_n, adj_n, (const float4*)b2, out, N_NODES);
}

// Round 17
// 193.964 us; speedup vs baseline: 1.8545x; 1.8545x over previous
//
#include <hip/hip_runtime.h>

#define N_NODES 50000
#define N_HEDGES 5000
#define NNZ 800000
#define IN_C 128
#define D1 256
#define D2 64
#define SN 64    // fixed stride: hedges per node row (deg mean 16, 12 sigma safe)
#define SH 256   // fixed stride: nodes per hedge row (deg mean 160, 7.6 sigma safe)

// dummy indices for adjacency padding (point at zeroed feature rows)
#define DUMN 50000   // dummy node index (row 50000 of xb/hwb zeroed)
#define DUMH 5000    // dummy hedge index (row 5000 of aggxb/e2b zeroed)

// bucketed adjacency build
#define HBK 20     // hedges per bucket
#define NHB 250    // hedge buckets
#define HCAP 4096  // pair capacity per hedge bucket (mean 3200, 16 sigma)
#define NBK 100    // nodes per bucket
#define NNB 500    // node buckets
#define NCAP 2048  // pair capacity per node bucket (mean 1600, 11 sigma)
#define BKT_BLOCKS ((NNZ + 2047) / 2048)   // 391

typedef unsigned int u32;
typedef unsigned short u16;
typedef __attribute__((ext_vector_type(8))) short short8;
typedef __attribute__((ext_vector_type(4))) float f32x4;

// ---- bf16 helpers: storage bf16, math f32 ----
__device__ __forceinline__ float bf_lo(u32 u) { return __uint_as_float(u << 16); }
__device__ __forceinline__ float bf_hi(u32 u) { return __uint_as_float(u & 0xffff0000u); }
__device__ __forceinline__ u32 rne16(float f) {
    u32 u = __float_as_uint(f);
    return (u + 0x7fffu + ((u >> 16) & 1u)) >> 16;
}
__device__ __forceinline__ u32 pack2(float a, float b) {
    return rne16(a) | (rne16(b) << 16);
}
__device__ __forceinline__ void acc8(float* a, uint4 v) {
    a[0] += bf_lo(v.x); a[1] += bf_hi(v.x);
    a[2] += bf_lo(v.y); a[3] += bf_hi(v.y);
    a[4] += bf_lo(v.z); a[5] += bf_hi(v.z);
    a[6] += bf_lo(v.w); a[7] += bf_hi(v.w);
}

// ---------------- fused: cast x->bf16 + pack W1/W2 + bucket edges + zero dummy rows ----------------
__global__ void cast_bucket(const float4* __restrict__ x, uint2* __restrict__ xb,
                            const float* __restrict__ W1, u16* __restrict__ w1hi,
                            u16* __restrict__ w1lo,
                            const float* __restrict__ W2, u16* __restrict__ w2hi,
                            u16* __restrict__ w2lo,
                            const int* __restrict__ nidx, const int* __restrict__ hidx,
                            int* __restrict__ gcur_h, int* __restrict__ gcur_n,
                            u32* __restrict__ pairs_h, u32* __restrict__ pairs_n,
                            uint4* __restrict__ xbz, uint4* __restrict__ aggz,
                            uint4* __restrict__ hwz, uint4* __restrict__ e2z) {
    __shared__ int hist_h[NHB], hist_n[NNB];
    __shared__ int base_h[NHB], base_n[NNB];
    int tid = threadIdx.x;
    int i = blockIdx.x * 256 + tid;
    float4 v = x[i];
    uint2 o;
    o.x = pack2(v.x, v.y);
    o.y = pack2(v.z, v.w);
    xb[i] = o;
    if (i < 32768) {  // W1: kc=0..3 (K=128), ct=0..15 (N=256)
        int j = i & 7;
        int l = (i >> 3) & 63;
        int ct = (i >> 9) & 15;
        int kc = i >> 13;
        int k = kc * 32 + (l >> 4) * 8 + j;
        int n = ct * 16 + (l & 15);
        float w = W1[k * D1 + n];
        u32 h = rne16(w);
        w1hi[i] = (u16)h;
        w1lo[i] = (u16)rne16(w - bf_lo(h));
    } else if (i < 32768 + 16384) {  // W2: kc=0..7 (K=256), nt=0..3 (N=64)
        int t = i - 32768;
        int j = t & 7;
        int l = (t >> 3) & 63;
        int nt = (t >> 9) & 3;
        int kc = t >> 11;
        int k = kc * 32 + (l >> 4) * 8 + j;
        int n = nt * 16 + (l & 15);
        float w = W2[k * D2 + n];
        u32 h = rne16(w);
        w2hi[t] = (u16)h;
        w2lo[t] = (u16)rne16(w - bf_lo(h));
    }
    // zero the dummy feature rows (gather targets for padded adjacency slots)
    if (blockIdx.x == gridDim.x - 1) {
        uint4 z = make_uint4(0u, 0u, 0u, 0u);
        if (tid < 16) xbz[tid] = z;            // xb row DUMN: 256 B
        else if (tid < 32) aggz[tid - 16] = z; // aggxb row DUMH: 256 B
        else if (tid < 40) hwz[tid - 32] = z;  // hwb row DUMN: 128 B
        else if (tid < 48) e2z[tid - 40] = z;  // e2b row DUMH: 128 B
    }
    if (blockIdx.x >= BKT_BLOCKS) return;
    for (int t = tid; t < NHB; t += 256) hist_h[t] = 0;
    for (int t = tid; t < NNB; t += 256) hist_n[t] = 0;
    __syncthreads();
    int e0 = blockIdx.x * 2048 + tid * 8;
    int ns[8], hs_[8];
#pragma unroll
    for (int k = 0; k < 8; k++) {
        int e = e0 + k;
        if (e < NNZ) {
            ns[k] = nidx[e];
            hs_[k] = hidx[e];
            atomicAdd(&hist_h[hs_[k] / HBK], 1);
            atomicAdd(&hist_n[ns[k] / NBK], 1);
        } else {
            ns[k] = -1;
        }
    }
    __syncthreads();
    if (tid < NHB) base_h[tid] = atomicAdd(&gcur_h[tid], hist_h[tid]);
    for (int t = tid; t < NNB; t += 256) base_n[t] = atomicAdd(&gcur_n[t], hist_n[t]);
    __syncthreads();
    for (int t = tid; t < NHB; t += 256) hist_h[t] = 0;
    for (int t = tid; t < NNB; t += 256) hist_n[t] = 0;
    __syncthreads();
#pragma unroll
    for (int k = 0; k < 8; k++) {
        if (ns[k] >= 0) {
            int n = ns[k], h = hs_[k];
            int bh = h / HBK, bn = n / NBK;
            int s1 = base_h[bh] + atomicAdd(&hist_h[bh], 1);
            if (s1 < HCAP) pairs_h[bh * HCAP + s1] = ((u32)h << 16) | (u32)n;
            int s2 = base_n[bn] + atomicAdd(&hist_n[bn], 1);
            if (s2 < NCAP) pairs_n[bn * NCAP + s2] = ((u32)n << 16) | (u32)h;
        }
    }
}

// ---------------- build adjacency rows in LDS, write coalesced (both sides) ----------------
__global__ void build_adj(const u32* __restrict__ pairs_h, const int* __restrict__ gcur_h,
                          u16* __restrict__ adj_h, int* __restrict__ cur_h,
                          const u32* __restrict__ pairs_n, const int* __restrict__ gcur_n,
                          u16* __restrict__ adj_n, int* __restrict__ cur_n) {
    __shared__ u16 rows[NBK * SN];  // 12.8 KB (>= HBK*SH = 10.24 KB)
    __shared__ int cnt[NBK];        // >= HBK
    int tid = threadIdx.x;
    if (blockIdx.x < NHB) {
        int b = blockIdx.x;
        if (tid < HBK) cnt[tid] = 0;
        {
            u32* rw = (u32*)rows;
            for (int t = tid; t < HBK * SH / 2; t += 256) rw[t] = (DUMN << 16) | DUMN;
        }
        __syncthreads();
        int np = gcur_h[b];
        if (np > HCAP) np = HCAP;
        for (int t = tid; t < np; t += 256) {
            u32 p = pairs_h[b * HCAP + t];
            int hl = (int)(p >> 16) - b * HBK;
            int s = atomicAdd(&cnt[hl], 1);
            if (s < SH) rows[hl * SH + s] = (u16)(p & 0xffff);
        }
        __syncthreads();
        u32* dst = (u32*)(adj_h + b * HBK * SH);
        const u32* srcl = (const u32*)rows;
        for (int t = tid; t < HBK * SH / 2; t += 256) dst[t] = srcl[t];
        if (tid < HBK) cur_h[b * HBK + tid] = cnt[tid];
    } else {
        int b = blockIdx.x - NHB;
        if (tid < NBK) cnt[tid] = 0;
        {
            u32* rw = (u32*)rows;
            for (int t = tid; t < NBK * SN / 2; t += 256) rw[t] = (DUMH << 16) | DUMH;
        }
        __syncthreads();
        int np = gcur_n[b];
        if (np > NCAP) np = NCAP;
        for (int t = tid; t < np; t += 256) {
            u32 p = pairs_n[b * NCAP + t];
            int nl = (int)(p >> 16) - b * NBK;
            int s = atomicAdd(&cnt[nl], 1);
            if (s < SN) rows[nl * SN + s] = (u16)(p & 0xffff);
        }
        __syncthreads();
        u32* dst = (u32*)(adj_n + b * NBK * SN);
        const u32* srcl = (const u32*)rows;
        for (int t = tid; t < NBK * SN / 2; t += 256) dst[t] = srcl[t];
        if (tid < NBK) cur_n[b * NBK + tid] = cnt[tid];
    }
}

// ---- shared gather core: remainder-free (dummy-padded adj), adj one group ahead ----
template <int L>
__device__ __forceinline__ void gcore(const uint4* __restrict__ src,
                                      const u16* __restrict__ arow,
                                      int js, int je, int c,
                                      float* a0, float* a1, float* a2, float* a3) {
    if (js >= je) return;
    uint4 aa = *(const uint4*)(arow + js);
    for (int j = js; j < je; j += 8) {
        uint4 nx = aa;
        if (j + 8 < je) nx = *(const uint4*)(arow + j + 8);
        int i0 = aa.x & 0xffff, i1 = aa.x >> 16;
        int i2 = aa.y & 0xffff, i3 = aa.y >> 16;
        int i4 = aa.z & 0xffff, i5 = aa.z >> 16;
        int i6 = aa.w & 0xffff, i7 = aa.w >> 16;
        uint4 v0 = src[i0 * L + c];
        uint4 v1 = src[i1 * L + c];
        uint4 v2 = src[i2 * L + c];
        uint4 v3 = src[i3 * L + c];
        uint4 v4 = src[i4 * L + c];
        uint4 v5 = src[i5 * L + c];
        uint4 v6 = src[i6 * L + c];
        uint4 v7 = src[i7 * L + c];
        acc8(a0, v0); acc8(a1, v1); acc8(a2, v2); acc8(a3, v3);
        acc8(a0, v4); acc8(a1, v5); acc8(a2, v6); acc8(a3, v7);
        aa = nx;
    }
}

// ---------------- split-K hedge gather: L*SPLIT threads/row, LDS combine ----------------
template <int F, int S, int SPLIT>
__global__ __launch_bounds__(256, 2)
void gather_split(const uint4* __restrict__ src, const int* __restrict__ cur,
                  const u16* __restrict__ adj, uint4* __restrict__ dst,
                  int nrows) {
    constexpr int L = F / 8;
    constexpr int TR = L * SPLIT;       // threads per row
    constexpr int RB = 256 / TR;        // rows per block
    constexpr int CHUNK = S / SPLIT;
    int tid = threadIdx.x;
    int rl = tid / TR;
    int seg = (tid % TR) / L;
    int c = tid % L;
    int row = blockIdx.x * RB + rl;
    bool valid = row < nrows;
    int len = valid ? cur[row] : 0;
    int lenc = (len < S) ? len : S;
    int lenp = (lenc + 7) & ~7;          // padded length (adj has dummies past cnt)
    int js = seg * CHUNK;
    int je = (lenp < js + CHUNK) ? lenp : (js + CHUNK);
    float a0[8] = {0,0,0,0,0,0,0,0}, a1[8] = {0,0,0,0,0,0,0,0};
    float a2[8] = {0,0,0,0,0,0,0,0}, a3[8] = {0,0,0,0,0,0,0,0};
    if (valid)
        gcore<L>(src, adj + row * S, js, je, c, a0, a1, a2, a3);
    // per-(rl,c,seg) partial -> LDS: RB*L*SPLIT*8 = 256*8 floats = 8KB
    __shared__ float partf[256][8];
#pragma unroll
    for (int t = 0; t < 8; t++) partf[tid][t] = ((a0[t] + a1[t]) + (a2[t] + a3[t]));
    __syncthreads();
    if (seg == 0 && valid) {
        float r[8];
#pragma unroll
        for (int t = 0; t < 8; t++) r[t] = partf[tid][t];
#pragma unroll
        for (int s2 = 1; s2 < SPLIT; s2++) {
#pragma unroll
            for (int t = 0; t < 8; t++) r[t] += partf[tid + s2 * L][t];
        }
        float inv = (len > 0) ? 1.f / (float)len : 0.f;
        uint4 o;
        o.x = pack2(r[0] * inv, r[1] * inv);
        o.y = pack2(r[2] * inv, r[3] * inv);
        o.z = pack2(r[4] * inv, r[5] * inv);
        o.w = pack2(r[6] * inv, r[7] * inv);
        dst[row * L + c] = o;
    }
}

// ---------------- bf16-source pull-gather (node side), vec-adj, remainder-free ----------------
template <int F, int S, bool BIAS_RELU, bool DST_BF16>
__global__ __launch_bounds__(256, 2)
void gatherb(const uint4* __restrict__ src, const int* __restrict__ cur,
             const u16* __restrict__ adj, const float4* __restrict__ bias,
             void* __restrict__ dst, int nrows) {
    constexpr int L = F / 8;
    int gid = blockIdx.x * 256 + threadIdx.x;
    int row = gid / L;
    if (row >= nrows) return;
    int c = gid - row * L;
    int len = cur[row];
    int lenc = (len < S) ? len : S;
    int lenp = (lenc + 7) & ~7;          // padded length (adj has dummies past cnt)
    float a0[8] = {0,0,0,0,0,0,0,0}, a1[8] = {0,0,0,0,0,0,0,0};
    float a2[8] = {0,0,0,0,0,0,0,0}, a3[8] = {0,0,0,0,0,0,0,0};
    gcore<L>(src, adj + row * S, 0, lenp, c, a0, a1, a2, a3);
    float inv = (len > 0) ? 1.f / (float)len : 0.f;
    float r[8];
#pragma unroll
    for (int t = 0; t < 8; t++) r[t] = ((a0[t] + a1[t]) + (a2[t] + a3[t])) * inv;
    if (BIAS_RELU) {
        float4 b0 = bias[c * 2], b1v = bias[c * 2 + 1];
        r[0] = fmaxf(r[0] + b0.x, 0.f); r[1] = fmaxf(r[1] + b0.y, 0.f);
        r[2] = fmaxf(r[2] + b0.z, 0.f); r[3] = fmaxf(r[3] + b0.w, 0.f);
        r[4] = fmaxf(r[4] + b1v.x, 0.f); r[5] = fmaxf(r[5] + b1v.y, 0.f);
        r[6] = fmaxf(r[6] + b1v.z, 0.f); r[7] = fmaxf(r[7] + b1v.w, 0.f);
    }
    if (DST_BF16) {
        uint4 o;
        o.x = pack2(r[0], r[1]);
        o.y = pack2(r[2], r[3]);
        o.z = pack2(r[4], r[5]);
        o.w = pack2(r[6], r[7]);
        ((uint4*)dst)[row * L + c] = o;
    } else {
        float4* d = (float4*)dst;
        d[row * (F / 4) + c * 2]     = make_float4(r[0], r[1], r[2], r[3]);
        d[row * (F / 4) + c * 2 + 1] = make_float4(r[4], r[5], r[6], r[7]);
    }
}

// ---------------- MLP: hw = relu(sb@W1+b1)@W2 — union-LDS rev ----------------
// r16 counters (6-rep): warm 31us/rep, MfmaUtil 12.5%, Occupancy 23.5% (<2
// blocks/CU resident; LDS 51.2KB capped 3/CU and each block opens with a cold
// HBM staging fetch). Fix: alias the sb staging buffer (17.4KB) and the output
// stage (9.2KB) INTO hs (33.8KB) -> LDS_Block_Size 33792 -> 4 blocks/CU, whole
// grid (3.05 blocks/CU) co-resident; staging/weight-load latencies overlap.
// W1 accumulators stay in regs until after a barrier, so the alias is safe.
// Two extra __syncthreads; identical math order -> bit-identical output.
#define SB_STRIDE 136
#define HSTRIDE 264
#define OSTR 72
__global__ __launch_bounds__(256, 3)
void mlp64(const uint4* __restrict__ sb4,
           const short8* __restrict__ w1hi, const short8* __restrict__ w1lo,
           const float* __restrict__ b1,
           const short8* __restrict__ w2hi, const short8* __restrict__ w2lo,
           u16* __restrict__ hw) {
    __shared__ u16 hs[64 * HSTRIDE];     // 33792 B total; low bytes alias sb/out stages
    u16* sbs = hs;                       // sb stage: 64*SB_STRIDE*2 = 17408 B
    int tid = threadIdx.x;
    int node0 = blockIdx.x * 64;
    int wave = tid >> 6;
    int lane = tid & 63;
    int m = lane & 15;
    int q = lane >> 4;
    // ---- phase 1: stage sb tile (64 nodes x 256 B), coalesced ----
    {
        int nl = tid >> 4;   // 0..15
        int c = tid & 15;    // uint4 col 0..15
#pragma unroll
        for (int p = 0; p < 4; p++) {
            uint4 v = sb4[(node0 + p * 16 + nl) * 16 + c];
            *(uint4*)&sbs[(p * 16 + nl) * SB_STRIDE + c * 8] = v;
        }
    }
    __syncthreads();
    // ---- phase 2: W1 compute (reads sbs; acc stays in registers) ----
    f32x4 acc[4][4];  // [i][mt], bias folded into init
#pragma unroll
    for (int i = 0; i < 4; i++) {
        float bc = b1[(wave * 4 + i) * 16 + m];
#pragma unroll
        for (int mt = 0; mt < 4; mt++)
            acc[i][mt] = (f32x4){bc, bc, bc, bc};
    }
#pragma unroll
    for (int kc = 0; kc < 4; kc++) {
        short8 am[4];
#pragma unroll
        for (int mt = 0; mt < 4; mt++)
            am[mt] = *(const short8*)&sbs[(mt * 16 + m) * SB_STRIDE + kc * 32 + q * 8];
        short8 w[4];
#pragma unroll
        for (int i = 0; i < 4; i++)
            w[i] = w1hi[(kc * 16 + wave * 4 + i) * 64 + lane];
#pragma unroll
        for (int i = 0; i < 4; i++)
#pragma unroll
            for (int mt = 0; mt < 4; mt++)
                acc[i][mt] = __builtin_amdgcn_mfma_f32_16x16x32_bf16(am[mt], w[i], acc[i][mt], 0, 0, 0);
#pragma unroll
        for (int i = 0; i < 4; i++)
            w[i] = w1lo[(kc * 16 + wave * 4 + i) * 64 + lane];
#pragma unroll
        for (int i = 0; i < 4; i++)
#pragma unroll
            for (int mt = 0; mt < 4; mt++)
                acc[i][mt] = __builtin_amdgcn_mfma_f32_16x16x32_bf16(am[mt], w[i], acc[i][mt], 0, 0, 0);
    }
    __syncthreads();   // all sbs reads complete -> hs may overwrite the alias
    // ---- phase 3: write hs from registers ----
#pragma unroll
    for (int i = 0; i < 4; i++) {
        int col = (wave * 4 + i) * 16 + m;   // C layout: col = lane&15, row = q*4+r
#pragma unroll
        for (int mt = 0; mt < 4; mt++)
#pragma unroll
            for (int r = 0; r < 4; r++) {
                float h = fmaxf(acc[i][mt][r], 0.f);
                hs[(mt * 16 + q * 4 + r) * HSTRIDE + col] = (u16)rne16(h);
            }
    }
    __syncthreads();
    // ---- phase 4: W2 compute (reads hs; acc2 in registers) ----
    f32x4 acc2[4];
#pragma unroll
    for (int mt = 0; mt < 4; mt++) acc2[mt] = (f32x4){0.f, 0.f, 0.f, 0.f};
#pragma unroll
    for (int kc = 0; kc < 8; kc++) {
        short8 ah[4];
#pragma unroll
        for (int mt = 0; mt < 4; mt++)
            ah[mt] = *(const short8*)&hs[(mt * 16 + m) * HSTRIDE + kc * 32 + q * 8];
        short8 whi = w2hi[(kc * 4 + wave) * 64 + lane];
#pragma unroll
        for (int mt = 0; mt < 4; mt++)
            acc2[mt] = __builtin_amdgcn_mfma_f32_16x16x32_bf16(ah[mt], whi, acc2[mt], 0, 0, 0);
        short8 wlo = w2lo[(kc * 4 + wave) * 64 + lane];
#pragma unroll
        for (int mt = 0; mt < 4; mt++)
            acc2[mt] = __builtin_amdgcn_mfma_f32_16x16x32_bf16(ah[mt], wlo, acc2[mt], 0, 0, 0);
    }
    __syncthreads();   // all hs reads complete -> out-stage may overwrite alias
    // ---- phase 5: gather output tile in LDS, coalesced 128B-line stores ----
#pragma unroll
    for (int mt = 0; mt < 4; mt++)
#pragma unroll
        for (int r = 0; r < 4; r++)
            hs[(mt * 16 + q * 4 + r) * OSTR + wave * 16 + m] = (u16)rne16(acc2[mt][r]);
    __syncthreads();
    {
        // 64 nodes x 8 uint4 (128 B) = 512 uint4; 256 threads x 2 passes
#pragma unroll
        for (int p = 0; p < 2; p++) {
            int idx = p * 256 + tid;
            int nl = idx >> 3;
            int c = idx & 7;
            int node = node0 + nl;
            if (node < N_NODES)
                ((uint4*)hw)[node * 8 + c] = *(const uint4*)&hs[nl * OSTR + c * 8];
        }
    }
}

extern "C" void kernel_launch(void* const* d_in, const int* in_sizes, int n_in,
                              void* d_out, int out_size, void* d_ws, size_t ws_size,
                              hipStream_t stream) {
    const float* x  = (const float*)d_in[0];
    const int* edge = (const int*)d_in[1];
    const int* nidx = edge;         // edge[0, :]
    const int* hidx = edge + NNZ;   // edge[1, :]
    const float* W1 = (const float*)d_in[2];
    const float* b1 = (const float*)d_in[3];
    const float* W2 = (const float*)d_in[4];
    const float* b2 = (const float*)d_in[5];
    float* out = (float*)d_out;

    // ---- workspace layout (all chunks 16B-aligned; +1 zeroed dummy row each) ----
    u16* xb     = (u16*)d_ws;                       // (50000+1)*128 u16
    u16* aggxb  = xb + (N_NODES + 1) * IN_C;        // (5000+1)*128  u16
    u16* hwb    = aggxb + (N_HEDGES + 1) * IN_C;    // (50000+1)*64  u16
    u16* e2b    = hwb + (N_NODES + 1) * D2;         // (5000+1)*64   u16
    u16* w1hi   = e2b + (N_HEDGES + 1) * D2;        // 32768 u16
    u16* w1lo   = w1hi + 32768;               // 32768 u16
    u16* w2hi   = w1lo + 32768;               // 16384 u16
    u16* w2lo   = w2hi + 16384;               // 16384 u16
    u16* adj_n  = w2lo + 16384;               // 50000*64 u16 = 3,200,000
    u16* adj_h  = adj_n + N_NODES * SN;       // 5000*256 u16 = 1,280,000
    u32* pairs_h = (u32*)(adj_h + N_HEDGES * SH); // 250*4096 u32 = 4 MB
    u32* pairs_n = pairs_h + NHB * HCAP;          // 500*2048 u32 = 4 MB
    int* cur_n  = (int*)(pairs_n + NNB * NCAP);   // 50000 (written by build)
    int* cur_h  = cur_n + N_NODES;                // 5000  (written by build)
    int* gcur_h = cur_h + N_HEDGES;               // 256 (zeroed)
    int* gcur_n = gcur_h + 256;                   // 512 (zeroed)
    u16* sb     = (u16*)(gcur_n + 512);           // 50048*128 u16 = 12.8 MB (padded tail)
    // total ≈ 52 MB

    hipMemsetAsync(gcur_h, 0, (256 + 512) * sizeof(int), stream);

    // fused: cast + W-pack + bucket + zero dummy rows
    cast_bucket<<<N_NODES * IN_C / 4 / 256, 256, 0, stream>>>(
        (const float4*)x, (uint2*)xb, W1, w1hi, w1lo, W2, w2hi, w2lo,
        nidx, hidx, gcur_h, gcur_n, pairs_h, pairs_n,
        (uint4*)(xb + DUMN * IN_C), (uint4*)(aggxb + DUMH * IN_C),
        (uint4*)(hwb + DUMN * D2), (uint4*)(e2b + DUMH * D2));

    build_adj<<<NHB + NNB, 256, 0, stream>>>(pairs_h, gcur_h, adj_h, cur_h,
                                             pairs_n, gcur_n, adj_n, cur_n);

    // aggxb = Binv * gather_h(xb)   [5000 x 128 bf16]  — split-K x4 (64 thr/row)
    gather_split<IN_C, SH, 4><<<(N_HEDGES + 3) / 4, 256, 0, stream>>>(
        (const uint4*)xb, cur_h, adj_h, (uint4*)aggxb, N_HEDGES);

    // sb = Dinv * gather_n(aggxb)   [50000 x 128 bf16] — no-LDS pull gather
    gatherb<IN_C, SN, false, true><<<(N_NODES * (IN_C / 8) + 255) / 256, 256, 0, stream>>>(
        (const uint4*)aggxb, cur_n, adj_n, (const float4*)b1, (void*)sb, N_NODES);

    // hw = relu(sb@W1+b1)@W2   [50000 x 64 bf16] — union-LDS (33.8KB -> 4 blk/CU)
    mlp64<<<(N_NODES + 63) / 64, 256, 0, stream>>>(
        (const uint4*)sb, (const short8*)w1hi, (const short8*)w1lo, b1,
        (const short8*)w2hi, (const short8*)w2lo, hwb);

    // layer 2: e2b = Binv * gather_h(hwb)  — split-K x8 (64 thr/row)
    gather_split<D2, SH, 8><<<(N_HEDGES + 3) / 4, 256, 0, stream>>>(
        (const uint4*)hwb, cur_h, adj_h, (uint4*)e2b, N_HEDGES);
    // out = relu(Dinv * gather_n(e2b) + b2)   [50000 x 64 f32]
    gatherb<D2, SN, true, false><<<(N_NODES * (D2 / 8) + 255) / 256, 256, 0, stream>>>(
        (const uint4*)e2b, cur_n, adj_n, (const float4*)b2, out, N_NODES);
}